// Round 7
// baseline (399.331 us; speedup 1.0000x reference)
//
#include <hip/hip_runtime.h>

// E^H D E exact NDFT as two complex MFMA GEMMs, R7 restructure:
//  * 32x32x16_f16 MFMA (2x FLOP per fragment byte vs 16x16x32)
//  * PLANAR complex (r/i fp16 planes; adj B planes stored conjugated):
//      Crp=mfma(Ar,B1) Crm=mfma(Ai,B2) Ci=mfma(Ar,B2)+mfma(Ai,B1) Cr=Crp-Crm
//    -> zero in-loop derive VALU (R6 spent ~128cyc/chunk on rot16/xor)
//  * barrier-free K-loops: fwd holds full A-tile in LDS (1 barrier total);
//    adj builds t2 in 2 fills (4 barriers/block vs R6's 32)
//  * B-fragments straight from global/L2 (offloads the LDS pipe)
//  * fwd split m-halves -> partial gP + combine_g; adj split-K=8 -> P + combine

#define NT 16
#define NK 2048
#define NXY 128
#define NC 8
#define ASPLIT 8

typedef _Float16 f16x8 __attribute__((ext_vector_type(8)));
typedef float f32x16 __attribute__((ext_vector_type(16)));

union F8 { f16x8 h; uint4 q; };

#define MFMA32(a, b, c) __builtin_amdgcn_mfma_f32_32x32x16_f16((a), (b), (c), 0, 0, 0)

__device__ __forceinline__ uint pack2h(float a, float b) {
    union { _Float16 h[2]; uint u; } p;
    p.h[0] = (_Float16)a; p.h[1] = (_Float16)b;
    return p.u;
}
__device__ __forceinline__ float2 unpack2h(uint v) {
    union { uint u; _Float16 h[2]; } p;
    p.u = v;
    return make_float2((float)p.h[0], (float)p.h[1]);
}
__device__ __forceinline__ ushort h1(float v) {
    union { _Float16 h; ushort u; } p;
    p.h = (_Float16)v;
    return p.u;
}

// ---------------------------------------------------------------------------
// kt2[p][t][k] = ktraj[p][k][t]; dcT[t][k] = dcomp[k][t]
// ---------------------------------------------------------------------------
__global__ __launch_bounds__(256) void meta_t(const float* __restrict__ ktraj,
                                              const float* __restrict__ dcomp,
                                              float* __restrict__ kt2,
                                              float* __restrict__ dcT) {
    const int row = blockIdx.x, p = row >> 4, t = row & 15;
    const float* src = (p < 2) ? (ktraj + (size_t)p * NK * NT) : dcomp;
    float* dst = (p < 2) ? (kt2 + ((size_t)p * NT + t) * NK) : (dcT + (size_t)t * NK);
    for (int k = threadIdx.x; k < NK; k += 256) dst[k] = src[(size_t)k * NT + t];
}

// ---------------------------------------------------------------------------
// ExCr/ExCi [t][k][x] fp16 planes of Ex = exp(+i*k*(64-x))  (fwd B)
// ---------------------------------------------------------------------------
__global__ __launch_bounds__(256) void prep_kp(const float* __restrict__ kt2,
                                               ushort* __restrict__ ExCr,
                                               ushort* __restrict__ ExCi) {
    const size_t idx = (size_t)blockIdx.x * 256 + threadIdx.x;
    const int x = idx & (NXY - 1);
    const int k = (idx >> 7) & (NK - 1);
    const int t = (int)(idx >> 18);
    const float kx = kt2[(size_t)t * NK + k];
    float s, c;
    __sincosf(kx * (float)(64 - x), &s, &c);
    ExCr[idx] = h1(c);
    ExCi[idx] = h1(s);
}

// ---------------------------------------------------------------------------
// ExTr/ExTn [t][x][k] planes of conj(Ex) = (cos, -sin)  (adj B),
// EyP [t][y][k] packed (cos,sin)  (adj build + fwd epilogue)
// ---------------------------------------------------------------------------
__global__ __launch_bounds__(256) void prep_x(const float* __restrict__ kt2,
                                              ushort* __restrict__ ExTr,
                                              ushort* __restrict__ ExTn,
                                              uint* __restrict__ EyP) {
    const size_t idx = (size_t)blockIdx.x * 256 + threadIdx.x;
    const int k = idx & (NK - 1);
    const int pos = (idx >> 11) & (NXY - 1);
    const int t = (int)(idx >> 18);
    const float kx = kt2[(size_t)t * NK + k];
    const float ky = kt2[(size_t)(NT + t) * NK + k];
    const float fx = (float)(64 - pos);
    float s, c;
    __sincosf(kx * fx, &s, &c);
    ExTr[idx] = h1(c);
    ExTn[idx] = h1(-s);
    __sincosf(ky * fx, &s, &c);
    EyP[idx] = pack2h(c, s);
}

// ---------------------------------------------------------------------------
// srcR/srcI [t][c][y][x] fp16 planes of smap*img  (fwd A)
// ---------------------------------------------------------------------------
__global__ __launch_bounds__(256) void prep_srcp(const float* __restrict__ xin,
                                                 const float* __restrict__ csmap,
                                                 ushort* __restrict__ srcR,
                                                 ushort* __restrict__ srcI) {
    const int idx = blockIdx.x * 256 + threadIdx.x;
    const int x = idx & 127, y = (idx >> 7) & 127, c = (idx >> 14) & 7, t = idx >> 17;
    const float ir = xin[(size_t)(x * NXY + y) * NT + t];
    const float ii = xin[(size_t)NXY * NXY * NT + (size_t)(x * NXY + y) * NT + t];
    const float sr = csmap[(size_t)c * 2 * NXY * NXY + x * NXY + y];
    const float si = csmap[(size_t)c * 2 * NXY * NXY + NXY * NXY + x * NXY + y];
    const size_t o = (size_t)((t * NC + c) * NXY + y) * NXY + x;
    srcR[o] = h1(sr * ir - si * ii);
    srcI[o] = h1(sr * ii + si * ir);
}

// ---------------------------------------------------------------------------
// fwd32: block=(t, c, z=kq*2+yh), 256 thr / 4 waves.
// C1[y(m)=64, kp(n)] = sum_x src*Ex. A (64x128 halves per plane) resident in
// LDS (one fill, one barrier, then barrier-free). Wave handles n-tiles
// nt = wv+4j of the block's 512-kp range; 8 k-steps of 16 x each.
// Epilogue: kdat partial over this y-half -> gP[yh][t][c][kp].
// ---------------------------------------------------------------------------
__global__ __launch_bounds__(256) void fwd32(const ushort* __restrict__ ExCr,
                                             const ushort* __restrict__ ExCi,
                                             const ushort* __restrict__ srcR,
                                             const ushort* __restrict__ srcI,
                                             const uint* __restrict__ EyP,
                                             float2* __restrict__ gP) {
    const int t = blockIdx.x, c = blockIdx.y;
    const int kq = blockIdx.z >> 1, yh = blockIdx.z & 1;
    const int tid = threadIdx.x, lane = tid & 63, wv = tid >> 6;
    const int l31 = lane & 31, lh = lane >> 5;

    __shared__ __align__(16) _Float16 Af[2][64][136];   // 136-half rows: 16B-aligned, conflict-free

    // one-shot A fill: plane p (128 thr each), half-row per thread
    {
        const int p = tid >> 7, row = (tid & 127) >> 1, xh = tid & 1;
        const ushort* sp = (p ? srcI : srcR) +
                           (((size_t)(t * NC + c) * NXY + yh * 64 + row) << 7) + xh * 64;
#pragma unroll
        for (int q = 0; q < 8; ++q) {
            uint4 v = *(const uint4*)(sp + q * 8);
            *(uint4*)&Af[p][row][xh * 64 + q * 8] = v;
        }
    }
    __syncthreads();

    for (int nt = wv; nt < 16; nt += 4) {
        const int kp = kq * 512 + nt * 32 + l31;
        const ushort* br = ExCr + (((size_t)t * NK + kp) << 7) + lh * 8;
        const ushort* bi = ExCi + (((size_t)t * NK + kp) << 7) + lh * 8;

        f32x16 crp[2], crm[2], ci[2];
#pragma unroll
        for (int mt = 0; mt < 2; ++mt) {
            crp[mt] = (f32x16)0.0f; crm[mt] = (f32x16)0.0f; ci[mt] = (f32x16)0.0f;
        }

#pragma unroll
        for (int ch = 0; ch < 8; ++ch) {
            F8 B1, B2;
            B1.q = *(const uint4*)(br + ch * 16);
            B2.q = *(const uint4*)(bi + ch * 16);
#pragma unroll
            for (int mt = 0; mt < 2; ++mt) {
                f16x8 Ar = *(const f16x8*)&Af[0][mt * 32 + l31][ch * 16 + lh * 8];
                f16x8 Ai = *(const f16x8*)&Af[1][mt * 32 + l31][ch * 16 + lh * 8];
                crp[mt] = MFMA32(Ar, B1.h, crp[mt]);
                crm[mt] = MFMA32(Ai, B2.h, crm[mt]);
                ci[mt]  = MFMA32(Ar, B2.h, ci[mt]);
                ci[mt]  = MFMA32(Ai, B1.h, ci[mt]);
            }
        }

        // epilogue: kdat partial (this y-half) = sum_y Ey[kp,y]*C1[y,kp]
        const uint* eyB = EyP + (size_t)t * NXY * NK + kp;
        float kdr = 0.f, kdi = 0.f;
#pragma unroll
        for (int mt = 0; mt < 2; ++mt) {
#pragma unroll
            for (int reg = 0; reg < 16; ++reg) {
                const int y = yh * 64 + mt * 32 + (reg & 3) + 8 * (reg >> 2) + 4 * lh;
                float2 ey = unpack2h(eyB[(size_t)y * NK]);
                float cr = crp[mt][reg] - crm[mt][reg];
                float cw = ci[mt][reg];
                kdr += ey.x * cr - ey.y * cw;
                kdi += ey.x * cw + ey.y * cr;
            }
        }
        kdr += __shfl_xor(kdr, 32);
        kdi += __shfl_xor(kdi, 32);
        if (lh == 0)
            gP[(((size_t)yh * NT + t) * NC + c) * NK + kp] = make_float2(kdr, kdi);
    }
}

// ---------------------------------------------------------------------------
// combine_g: g[t][c][kp] = (gP[0] + gP[1]) * dcomp * scale^2
// ---------------------------------------------------------------------------
__global__ __launch_bounds__(256) void combine_g(const float2* __restrict__ gP,
                                                 const float* __restrict__ dcT,
                                                 float2* __restrict__ g) {
    const size_t i = (size_t)blockIdx.x * 256 + threadIdx.x;   // (t*NC+c)*NK+kp
    const int kp = (int)(i & (NK - 1));
    const int t = (int)(i >> 14);
    float2 a = gP[i], b = gP[(size_t)NT * NC * NK + i];
    const float w = dcT[(size_t)t * NK + kp] * (1.0f / 16384.0f);
    g[i] = make_float2((a.x + b.x) * w, (a.y + b.y) * w);
}

// ---------------------------------------------------------------------------
// adj32: block=(t, yt of 8 y, sp of 256 kp), 256 thr / 4 waves.
// C3[m=(yloc*8+c)=64, x(n)=128] = sum_kp t2 * conj(Ex).
// A = t2 = conj(Ey)*g built planar in LDS, 2 fills of 128 kp (4 barriers).
// B = conj(Ex) planes from global. Wave owns x-tile wv*32.
// Epilogue: coil-combine with conj(smap) -> P[sp][t][y][x].
// ---------------------------------------------------------------------------
__global__ __launch_bounds__(256) void adj32(const ushort* __restrict__ ExTr,
                                             const ushort* __restrict__ ExTn,
                                             const uint* __restrict__ EyP,
                                             const float2* __restrict__ g,
                                             const float* __restrict__ csmap,
                                             float2* __restrict__ P) {
    const int t = blockIdx.x, yt = blockIdx.y, sp = blockIdx.z;
    const int tid = threadIdx.x, lane = tid & 63, wv = tid >> 6;
    const int l31 = lane & 31, lh = lane >> 5;
    const int x = wv * 32 + l31;

    __shared__ __align__(16) _Float16 Ts[2][64][136];

    f32x16 crp[2], crm[2], ci[2];
#pragma unroll
    for (int mt = 0; mt < 2; ++mt) {
        crp[mt] = (f32x16)0.0f; crm[mt] = (f32x16)0.0f; ci[mt] = (f32x16)0.0f;
    }

    const ushort* brB = ExTr + ((size_t)(t * NXY + x)) * NK + sp * 256 + lh * 8;
    const ushort* biB = ExTn + ((size_t)(t * NXY + x)) * NK + sp * 256 + lh * 8;

    // build mapping: row = tid>>2 (yloc*8+c), kp-quarter = tid&3 (32 kp)
    const int brow = tid >> 2, bkq = tid & 3;
    const int by = yt * 8 + (brow >> 3), bc = brow & 7;
    const float2* gc = g + ((size_t)t * NC + bc) * NK + sp * 256;
    const uint* eyc = EyP + ((size_t)t * NXY + by) * NK + sp * 256;

    for (int half = 0; half < 2; ++half) {
        __syncthreads();
        // build t2 planar: 64 rows x 128 kp
#pragma unroll
        for (int j8 = 0; j8 < 4; ++j8) {
            const int kk = half * 128 + bkq * 32 + j8 * 8;   // block-relative kp
            float4 g0 = *(const float4*)(gc + kk);
            float4 g1 = *(const float4*)(gc + kk + 2);
            float4 g2 = *(const float4*)(gc + kk + 4);
            float4 g3 = *(const float4*)(gc + kk + 6);
            uint4 e0 = *(const uint4*)(eyc + kk);
            uint4 e1 = *(const uint4*)(eyc + kk + 4);
            float tr[8], ti[8];
            float2 ey;
            ey = unpack2h(e0.x); tr[0] = ey.x*g0.x + ey.y*g0.y; ti[0] = ey.x*g0.y - ey.y*g0.x;
            ey = unpack2h(e0.y); tr[1] = ey.x*g0.z + ey.y*g0.w; ti[1] = ey.x*g0.w - ey.y*g0.z;
            ey = unpack2h(e0.z); tr[2] = ey.x*g1.x + ey.y*g1.y; ti[2] = ey.x*g1.y - ey.y*g1.x;
            ey = unpack2h(e0.w); tr[3] = ey.x*g1.z + ey.y*g1.w; ti[3] = ey.x*g1.w - ey.y*g1.z;
            ey = unpack2h(e1.x); tr[4] = ey.x*g2.x + ey.y*g2.y; ti[4] = ey.x*g2.y - ey.y*g2.x;
            ey = unpack2h(e1.y); tr[5] = ey.x*g2.z + ey.y*g2.w; ti[5] = ey.x*g2.w - ey.y*g2.z;
            ey = unpack2h(e1.z); tr[6] = ey.x*g3.x + ey.y*g3.y; ti[6] = ey.x*g3.y - ey.y*g3.x;
            ey = unpack2h(e1.w); tr[7] = ey.x*g3.z + ey.y*g3.w; ti[7] = ey.x*g3.w - ey.y*g3.z;
            uint4 wr, wi;
            wr.x = pack2h(tr[0], tr[1]); wr.y = pack2h(tr[2], tr[3]);
            wr.z = pack2h(tr[4], tr[5]); wr.w = pack2h(tr[6], tr[7]);
            wi.x = pack2h(ti[0], ti[1]); wi.y = pack2h(ti[2], ti[3]);
            wi.z = pack2h(ti[4], ti[5]); wi.w = pack2h(ti[6], ti[7]);
            const int col = bkq * 32 + j8 * 8;
            *(uint4*)&Ts[0][brow][col] = wr;
            *(uint4*)&Ts[1][brow][col] = wi;
        }
        __syncthreads();

        const ushort* br = brB + half * 128;
        const ushort* bi = biB + half * 128;
#pragma unroll
        for (int ks = 0; ks < 8; ++ks) {
            F8 B1, B2;
            B1.q = *(const uint4*)(br + ks * 16);
            B2.q = *(const uint4*)(bi + ks * 16);
#pragma unroll
            for (int mt = 0; mt < 2; ++mt) {
                f16x8 Ar = *(const f16x8*)&Ts[0][mt * 32 + l31][ks * 16 + lh * 8];
                f16x8 Ai = *(const f16x8*)&Ts[1][mt * 32 + l31][ks * 16 + lh * 8];
                crp[mt] = MFMA32(Ar, B1.h, crp[mt]);
                crm[mt] = MFMA32(Ai, B2.h, crm[mt]);
                ci[mt]  = MFMA32(Ar, B2.h, ci[mt]);
                ci[mt]  = MFMA32(Ai, B1.h, ci[mt]);
            }
        }
    }

    // epilogue: coil-combine with conj(smap) -> P[sp][t][y][x]
#pragma unroll
    for (int mt = 0; mt < 2; ++mt) {
#pragma unroll
        for (int p = 0; p < 4; ++p) {
            const int y = yt * 8 + mt * 4 + p;
            float or_ = 0.f, oi_ = 0.f;
#pragma unroll
            for (int q = 0; q < 4; ++q) {
                const int reg = p * 4 + q;          // row32 = q + 8p + 4lh
                const int cc = lh * 4 + q;
                float xr = crp[mt][reg] - crm[mt][reg];
                float xi = ci[mt][reg];
                float sr = csmap[(size_t)(cc * 2) * NXY * NXY + x * NXY + y];
                float si = csmap[(size_t)(cc * 2 + 1) * NXY * NXY + x * NXY + y];
                or_ += sr * xr + si * xi;
                oi_ += sr * xi - si * xr;
            }
            or_ += __shfl_xor(or_, 32);
            oi_ += __shfl_xor(oi_, 32);
            if (lh == 0)
                P[(((size_t)sp * NT + t) * NXY + y) * NXY + x] = make_float2(or_, oi_);
        }
    }
}

// ---------------------------------------------------------------------------
// combine: out[p][x][y][t] = sum_sp P[sp][t][y][x].p  (R5-proven)
// ---------------------------------------------------------------------------
__global__ __launch_bounds__(256) void combine(const float2* __restrict__ P,
                                               float* __restrict__ out) {
    const int y = blockIdx.x, xb = blockIdx.y * 16;
    const int tid = threadIdx.x;
    __shared__ float2 tile[16][17];
    {
        const int xl = tid & 15, tt = tid >> 4;
        float2 s = make_float2(0.f, 0.f);
#pragma unroll
        for (int sp = 0; sp < ASPLIT; ++sp) {
            float2 v = P[((size_t)(sp * NT + tt) * NXY + y) * NXY + xb + xl];
            s.x += v.x; s.y += v.y;
        }
        tile[tt][xl] = s;
    }
    __syncthreads();
    {
        const int tt = tid & 15, xl = tid >> 4;
        float2 v = tile[tt][xl];
        const int x = xb + xl;
        out[((size_t)x * NXY + y) * NT + tt] = v.x;
        out[(size_t)NXY * NXY * NT + ((size_t)x * NXY + y) * NT + tt] = v.y;
    }
}

// ---------------------------------------------------------------------------
extern "C" void kernel_launch(void* const* d_in, const int* in_sizes, int n_in,
                              void* d_out, int out_size, void* d_ws, size_t ws_size,
                              hipStream_t stream) {
    const float* xin   = (const float*)d_in[0];
    const float* ktraj = (const float*)d_in[1];
    const float* csmap = (const float*)d_in[2];
    const float* dcomp = (const float*)d_in[3];
    float* out = (float*)d_out;

    const size_t TBL = (size_t)NT * NK * NXY;          // 4,194,304 elements
    float* kt2   = (float*)d_ws;                       // [2][t][k]
    float* dcT   = kt2 + (size_t)2 * NT * NK;          // [t][k]
    ushort* ExCr = (ushort*)(dcT + (size_t)NT * NK);   // [t][k][x] 8MB
    ushort* ExCi = ExCr + TBL;                         // 8MB
    ushort* ExTr = ExCi + TBL;                         // [t][x][k] 8MB
    ushort* ExTn = ExTr + TBL;                         // 8MB (pre-negated sin)
    uint*  EyP   = (uint*)(ExTn + TBL);                // [t][y][k] packed 16MB
    ushort* srcR = (ushort*)(EyP + TBL);               // [t][c][y][x] 2MB
    ushort* srcI = srcR + (size_t)NT * NC * NXY * NXY; // 2MB
    float2* gP   = (float2*)(srcI + (size_t)NT * NC * NXY * NXY);  // [yh][t][c][k] 4MB
    float2* g    = gP + (size_t)2 * NT * NC * NK;      // [t][c][k] 2MB
    float2* P    = (float2*)ExCr;  // partials alias ExC planes (dead after fwd32): 16MB exact

    meta_t<<<3 * NT, 256, 0, stream>>>(ktraj, dcomp, kt2, dcT);
    prep_kp<<<(int)(TBL / 256), 256, 0, stream>>>(kt2, ExCr, ExCi);
    prep_x<<<(int)(TBL / 256), 256, 0, stream>>>(kt2, ExTr, ExTn, EyP);
    prep_srcp<<<(NT * NC * NXY * NXY) / 256, 256, 0, stream>>>(xin, csmap, srcR, srcI);
    fwd32<<<dim3(NT, NC, 8), 256, 0, stream>>>(ExCr, ExCi, srcR, srcI, EyP, gP);
    combine_g<<<(int)((size_t)NT * NC * NK / 256), 256, 0, stream>>>(gP, dcT, g);
    adj32<<<dim3(NT, NXY / 8, ASPLIT), 256, 0, stream>>>(ExTr, ExTn, EyP, g, csmap, P);
    combine<<<dim3(NXY, NXY / 16), 256, 0, stream>>>(P, out);
}